// Round 1
// baseline (556.037 us; speedup 1.0000x reference)
//
#include <hip/hip_runtime.h>
#include <hip/hip_bf16.h>
#include <stdint.h>

typedef __bf16 bf16x8 __attribute__((ext_vector_type(8)));
typedef float  f32x4  __attribute__((ext_vector_type(4)));

#define DEV __device__ __forceinline__

constexpr int SUBJ  = 4;
constexpr int IN    = 4096;
constexpr int H     = 2048;
constexpr int DEPTH = 6;
constexpr int BATCH = 1024;
constexpr int BOT   = 128;
constexpr int IMG   = 768;
constexpr int TXT   = 768;
constexpr int MP    = 1408;   // padded sorted rows (worst case: 4 groups each padded to 128)
constexpr int MT    = 11;     // MP/128 row tiles

DEV float gelu_exact(float x){ return 0.5f*x*(1.0f + erff(x*0.70710678118654752440f)); }

// ---------------- subject counting-sort (1 block, 1024 threads) ----------------
__global__ void sort_kernel(const int* __restrict__ ids, int* __restrict__ rowmap,
                            int* __restrict__ tileS){
  __shared__ int hist[16][4];
  __shared__ int basew[16][4];
  __shared__ int pstart[5];
  int tid = threadIdx.x;
  if (tid < MP) rowmap[tid] = -1;
  if (tid + 1024 < MP) rowmap[tid + 1024] = -1;
  int w = tid >> 6, lane = tid & 63;
  int my = ids[tid];
  unsigned long long mymask = 0ull;
  #pragma unroll
  for (int s = 0; s < 4; ++s){
    unsigned long long m = __ballot(my == s);
    if (lane == 0) hist[w][s] = (int)__popcll(m);
    if (s == my) mymask = m;
  }
  int myrank = (int)__popcll(mymask & ((1ull << lane) - 1ull));
  __syncthreads();
  if (tid == 0){
    for (int s = 0; s < 4; ++s){
      int run = 0;
      for (int ww = 0; ww < 16; ++ww){ basew[ww][s] = run; run += hist[ww][s]; }
      hist[0][s] = run;                               // total count of subject s
    }
    pstart[0] = 0;
    for (int s = 0; s < 4; ++s) pstart[s+1] = pstart[s] + ((hist[0][s] + 127) & ~127);
  }
  __syncthreads();
  int pos = pstart[my] + basew[w][my] + myrank;
  rowmap[pos] = tid;                                  // sorted pos -> original row
  if (tid < MT){
    int row0 = tid << 7, s = -1;
    for (int ss = 0; ss < 4; ++ss) if (row0 >= pstart[ss] && row0 < pstart[ss+1]) s = ss;
    tileS[tid] = s;                                   // subject per 128-row tile (-1 = inactive)
  }
}

// ---------------- fp32 [K][N] -> bf16 [N][K] transpose+convert (all weights, 1 launch) ----
struct TMat { const float* src; __hip_bfloat16* dst; int K, N, batch, NT, tile0; };
struct TParams { TMat m[6]; };

__global__ void transpose_convert(TParams p){
  int bid = blockIdx.x, tid = threadIdx.x;
  int mi = 0;
  #pragma unroll
  for (int i = 1; i < 6; ++i) if (bid >= p.m[i].tile0) mi = i;
  TMat t = p.m[mi];
  int local = bid - t.tile0;
  int KT = t.K >> 6;
  int tpb = KT * t.NT;
  int b = local / tpb; int rem = local - b * tpb;
  int kt = rem / t.NT, nt = rem - kt * t.NT;
  const float* src = t.src + (size_t)b * t.K * t.N;
  __hip_bfloat16* dst = t.dst + (size_t)b * t.K * t.N;
  int k0 = kt << 6, n0 = nt << 6;
  __shared__ float tile[64][65];
  #pragma unroll
  for (int i = 0; i < 4; ++i){
    int row = i*16 + (tid >> 4);
    int col = (tid & 15) << 2;
    float4 v = *reinterpret_cast<const float4*>(src + (size_t)(k0+row)*t.N + n0 + col);
    tile[row][col+0] = v.x; tile[row][col+1] = v.y; tile[row][col+2] = v.z; tile[row][col+3] = v.w;
  }
  __syncthreads();
  #pragma unroll
  for (int i = 0; i < 2; ++i){
    int cell = i*256 + tid;
    int n = cell >> 3, kc = cell & 7;
    __hip_bfloat16 v[8];
    #pragma unroll
    for (int j = 0; j < 8; ++j) v[j] = __float2bfloat16(tile[kc*8 + j][n]);
    *reinterpret_cast<uint4*>(dst + (size_t)(n0+n)*t.K + k0 + kc*8) = *reinterpret_cast<const uint4*>(v);
  }
}

// ---------------- gather voxels into sorted order, fp32 -> bf16 ----------------
__global__ void gather_voxels(const float* __restrict__ vox, const int* __restrict__ rowmap,
                              __hip_bfloat16* __restrict__ Vs){
  int r = blockIdx.x, tid = threadIdx.x;
  int orig = rowmap[r];
  #pragma unroll
  for (int i = 0; i < 4; ++i){
    int c = (i*256 + tid) << 2;
    float4 v = {0.f,0.f,0.f,0.f};
    if (orig >= 0) v = *reinterpret_cast<const float4*>(vox + (size_t)orig*IN + c);
    __hip_bfloat16 o[4] = {__float2bfloat16(v.x), __float2bfloat16(v.y),
                           __float2bfloat16(v.z), __float2bfloat16(v.w)};
    *reinterpret_cast<uint2*>(Vs + (size_t)r*IN + c) = *reinterpret_cast<const uint2*>(o);
  }
}

// ---------------- 128x128 tile MFMA GEMM, A [M][K] bf16, B' [N][K] bf16 ----------------
enum { EPI_ATOMIC = 0, EPI_RES_BF16 = 1, EPI_F32 = 2, EPI_HEAD = 3 };

template<int EPI>
__global__ __launch_bounds__(256, 2)
void gemm_bf16(const __hip_bfloat16* __restrict__ A, int lda,
               const __hip_bfloat16* __restrict__ Bw, int ldb, long long wsub,
               const int* __restrict__ tileS, const int* __restrict__ rowmap,
               int ksplit,
               const float* __restrict__ bias, int biassub,
               const float* __restrict__ resid, int ldres,
               float* __restrict__ outf, __hip_bfloat16* __restrict__ outb, int ldo)
{
  int mt = blockIdx.x, nt = blockIdx.y;
  int s = tileS[mt];
  if (s < 0) return;                       // inactive (pad) row tile
  const __hip_bfloat16* Ab = A + (size_t)mt*128*lda;
  const __hip_bfloat16* Bb = Bw + (size_t)s*wsub + (size_t)nt*128*ldb;
  int kb = blockIdx.z * ksplit;
  int nk = ksplit >> 6;

  __shared__ __hip_bfloat16 sA[2][128*64];
  __shared__ __hip_bfloat16 sB[2][128*64];

  int tid = threadIdx.x;
  int lane = tid & 63;
  int wv = tid >> 6, wr = wv >> 1, wc = wv & 1;

  f32x4 acc[4][4];
  #pragma unroll
  for (int i = 0; i < 4; ++i)
    #pragma unroll
    for (int j = 0; j < 4; ++j) acc[i][j] = (f32x4){0.f,0.f,0.f,0.f};

  // stage one 128x64 bf16 tile of A and B into LDS via global_load_lds (16B/lane).
  // LDS is linear; global source is XOR-pre-swizzled (cell ^ (row&7)) so the swizzled
  // ds_read below is conflict-free (T2, both-sides rule #21).
  auto stage = [&](int buf, int k0){
    #pragma unroll
    for (int i = 0; i < 4; ++i){
      int cell = i*256 + tid;
      int row = cell >> 3, cc = cell & 7;
      int kg = k0 + ((cc ^ (row & 7)) << 3);
      __builtin_amdgcn_global_load_lds(
        (const __attribute__((address_space(1))) void*)(Ab + (size_t)row*lda + kg),
        (__attribute__((address_space(3))) void*)(&sA[buf][cell<<3]), 16, 0, 0);
      __builtin_amdgcn_global_load_lds(
        (const __attribute__((address_space(1))) void*)(Bb + (size_t)row*ldb + kg),
        (__attribute__((address_space(3))) void*)(&sB[buf][cell<<3]), 16, 0, 0);
    }
  };

  stage(0, kb);
  __syncthreads();
  for (int t = 0; t < nk; ++t){
    if (t+1 < nk) stage((t+1)&1, kb + ((t+1)<<6));
    const char* baseA = (const char*)(&sA[t&1][0]);
    const char* baseB = (const char*)(&sB[t&1][0]);
    int rA = (wr<<6) + (lane & 15);
    int rB = (wc<<6) + (lane & 15);
    #pragma unroll
    for (int kk = 0; kk < 2; ++kk){
      int koff = ((((kk<<5) + ((lane>>4)<<3)) << 1)) ^ ((lane & 7) << 4);
      bf16x8 av[4], bv[4];
      #pragma unroll
      for (int f = 0; f < 4; ++f){
        av[f] = *reinterpret_cast<const bf16x8*>(baseA + (size_t)(rA + f*16)*128 + koff);
        bv[f] = *reinterpret_cast<const bf16x8*>(baseB + (size_t)(rB + f*16)*128 + koff);
      }
      #pragma unroll
      for (int i = 0; i < 4; ++i)
        #pragma unroll
        for (int j = 0; j < 4; ++j)
          acc[i][j] = __builtin_amdgcn_mfma_f32_16x16x32_bf16(av[i], bv[j], acc[i][j], 0, 0, 0);
    }
    __syncthreads();
  }

  // epilogue; C/D layout (m89-verified): col = lane&15, row = (lane>>4)*4 + reg
  #pragma unroll
  for (int i = 0; i < 4; ++i){
    int rbase = (mt<<7) + (wr<<6) + (i<<4) + ((lane>>4)<<2);
    #pragma unroll
    for (int j = 0; j < 4; ++j){
      int col = (nt<<7) + (wc<<6) + (j<<4) + (lane & 15);
      #pragma unroll
      for (int q = 0; q < 4; ++q){
        int r = rbase + q;
        float v = acc[i][j][q];
        if constexpr (EPI == EPI_ATOMIC){
          atomicAdd(outf + (size_t)r*ldo + col, v);
        } else if constexpr (EPI == EPI_RES_BF16){
          int orig = rowmap[r];
          if (orig >= 0){
            v += bias[(size_t)s*biassub + col] + resid[(size_t)orig*ldres + col];
            outb[(size_t)r*ldo + col] = __float2bfloat16(v);
          }
        } else if constexpr (EPI == EPI_F32){
          outf[(size_t)r*ldo + col] = v + bias[(size_t)s*biassub + col];
        } else { // EPI_HEAD: scatter back to original row order
          int orig = rowmap[r];
          if (orig >= 0) outf[(size_t)orig*ldo + col] = v + bias[col];
        }
      }
    }
  }
}

// ---------------- T1 = gelu(T1acc + db[s])  (bf16) ----------------
__global__ void t1_epilogue(const float* __restrict__ acc, const float* __restrict__ db,
                            const int* __restrict__ rowmap, const int* __restrict__ tileS,
                            __hip_bfloat16* __restrict__ T1){
  int idx = blockIdx.x*256 + threadIdx.x;
  int r = idx >> 7, c = idx & 127;
  float v = 0.f;
  if (rowmap[r] >= 0){
    int s = tileS[r >> 7];
    v = gelu_exact(acc[idx] + db[s*BOT + c]);
  }
  T1[idx] = __float2bfloat16(v);
}

// ---------------- row LayerNorm + gelu (+optional residual), writes fp32 X and bf16 X ----
template<int RES>
__global__ void ln_gelu_kernel(const float* __restrict__ Z, const float* __restrict__ g,
                               const float* __restrict__ b, int gsub,
                               const int* __restrict__ tileS, const int* __restrict__ rowmap,
                               float* __restrict__ Xf, __hip_bfloat16* __restrict__ Xb){
  int r = blockIdx.x, tid = threadIdx.x;
  size_t rowoff = (size_t)r * H;
  int c0 = tid << 3;
  int orig = rowmap[r];
  if (orig < 0){
    float4 zf = {0.f,0.f,0.f,0.f};
    *reinterpret_cast<float4*>(Xf + rowoff + c0)     = zf;
    *reinterpret_cast<float4*>(Xf + rowoff + c0 + 4) = zf;
    uint4 zu = {0u,0u,0u,0u};
    *reinterpret_cast<uint4*>(Xb + rowoff + c0) = zu;
    return;
  }
  float z[8];
  float4 v1 = *reinterpret_cast<const float4*>(Z + rowoff + c0);
  float4 v2 = *reinterpret_cast<const float4*>(Z + rowoff + c0 + 4);
  z[0]=v1.x; z[1]=v1.y; z[2]=v1.z; z[3]=v1.w;
  z[4]=v2.x; z[5]=v2.y; z[6]=v2.z; z[7]=v2.w;
  float s1 = 0.f, s2 = 0.f;
  #pragma unroll
  for (int j = 0; j < 8; ++j){ s1 += z[j]; s2 += z[j]*z[j]; }
  #pragma unroll
  for (int m = 32; m >= 1; m >>= 1){ s1 += __shfl_xor(s1, m); s2 += __shfl_xor(s2, m); }
  __shared__ float red[4][2];
  int wv = tid >> 6, lane = tid & 63;
  if (lane == 0){ red[wv][0] = s1; red[wv][1] = s2; }
  __syncthreads();
  s1 = red[0][0]+red[1][0]+red[2][0]+red[3][0];
  s2 = red[0][1]+red[1][1]+red[2][1]+red[3][1];
  const float invH = 1.f / (float)H;
  float mu  = s1 * invH;
  float var = s2 * invH - mu*mu;
  float rs  = rsqrtf(var + 1e-5f);
  int si = gsub ? tileS[r>>7] : 0;
  const float* gp = g + (size_t)si*gsub;
  const float* bp = b + (size_t)si*gsub;
  float o[8];
  #pragma unroll
  for (int j = 0; j < 8; ++j){
    float t = (z[j]-mu)*rs*gp[c0+j] + bp[c0+j];
    o[j] = gelu_exact(t);
  }
  if constexpr (RES){
    float4 x1 = *reinterpret_cast<const float4*>(Xf + rowoff + c0);
    float4 x2 = *reinterpret_cast<const float4*>(Xf + rowoff + c0 + 4);
    o[0]+=x1.x; o[1]+=x1.y; o[2]+=x1.z; o[3]+=x1.w;
    o[4]+=x2.x; o[5]+=x2.y; o[6]+=x2.z; o[7]+=x2.w;
  }
  float4 w1 = {o[0],o[1],o[2],o[3]}, w2 = {o[4],o[5],o[6],o[7]};
  *reinterpret_cast<float4*>(Xf + rowoff + c0)     = w1;
  *reinterpret_cast<float4*>(Xf + rowoff + c0 + 4) = w2;
  __hip_bfloat16 ob[8];
  #pragma unroll
  for (int j = 0; j < 8; ++j) ob[j] = __float2bfloat16(o[j]);
  *reinterpret_cast<uint4*>(Xb + rowoff + c0) = *reinterpret_cast<const uint4*>(ob);
}

// ------------------------------------------------------------------------------
extern "C" void kernel_launch(void* const* d_in, const int* in_sizes, int n_in,
                              void* d_out, int out_size, void* d_ws, size_t ws_size,
                              hipStream_t stream){
  (void)in_sizes; (void)n_in; (void)out_size; (void)ws_size;
  const float* vox       = (const float*)d_in[0];
  const int*   ids       = (const int*)  d_in[1];
  const float* ad_down_w = (const float*)d_in[2];
  const float* ad_down_b = (const float*)d_in[3];
  const float* ad_up_w   = (const float*)d_in[4];
  const float* ad_up_b   = (const float*)d_in[5];
  const float* enc_w     = (const float*)d_in[6];
  const float* enc_b     = (const float*)d_in[7];
  const float* enc_ln_g  = (const float*)d_in[8];
  const float* enc_ln_bb = (const float*)d_in[9];
  const float* bb_w      = (const float*)d_in[10];
  const float* bb_b      = (const float*)d_in[11];
  const float* bb_ln_g   = (const float*)d_in[12];
  const float* bb_ln_b   = (const float*)d_in[13];
  const float* img_w     = (const float*)d_in[14];
  const float* img_b     = (const float*)d_in[15];
  const float* txt_w     = (const float*)d_in[16];
  const float* txt_b     = (const float*)d_in[17];
  float* out = (float*)d_out;

  char* wp = (char*)d_ws;
  auto alloc = [&](size_t bytes)->char*{ char* p = wp; wp += (bytes + 255) & ~(size_t)255; return p; };
  int* rowmap = (int*)alloc(MP * sizeof(int));
  int* tileS  = (int*)alloc(MT * sizeof(int));
  __hip_bfloat16* Vs    = (__hip_bfloat16*)alloc((size_t)MP*IN*2);
  __hip_bfloat16* wadT  = (__hip_bfloat16*)alloc((size_t)SUBJ*IN*BOT*2);
  __hip_bfloat16* wupT  = (__hip_bfloat16*)alloc((size_t)SUBJ*IN*BOT*2);
  __hip_bfloat16* wencT = (__hip_bfloat16*)alloc((size_t)SUBJ*IN*H*2);
  __hip_bfloat16* wbbT  = (__hip_bfloat16*)alloc((size_t)DEPTH*H*H*2);
  __hip_bfloat16* wimgT = (__hip_bfloat16*)alloc((size_t)H*IMG*2);
  __hip_bfloat16* wtxtT = (__hip_bfloat16*)alloc((size_t)H*TXT*2);
  float* T1acc          = (float*)alloc((size_t)MP*BOT*4);
  __hip_bfloat16* T1    = (__hip_bfloat16*)alloc((size_t)MP*BOT*2);
  __hip_bfloat16* Hs    = (__hip_bfloat16*)alloc((size_t)MP*IN*2);
  float* Z              = (float*)alloc((size_t)MP*H*4);
  float* Xf             = (float*)alloc((size_t)MP*H*4);
  __hip_bfloat16* Xb    = (__hip_bfloat16*)alloc((size_t)MP*H*2);

  sort_kernel<<<1, 1024, 0, stream>>>(ids, rowmap, tileS);

  TParams tp; int cum = 0;
  auto setm = [&](int i, const float* s, __hip_bfloat16* d, int K, int N, int batch){
    tp.m[i].src = s; tp.m[i].dst = d; tp.m[i].K = K; tp.m[i].N = N; tp.m[i].batch = batch;
    tp.m[i].NT = N/64; tp.m[i].tile0 = cum; cum += (K/64)*(N/64)*batch; };
  setm(0, ad_down_w, wadT,  IN,  BOT, SUBJ);
  setm(1, ad_up_w,   wupT,  BOT, IN,  SUBJ);
  setm(2, enc_w,     wencT, IN,  H,   SUBJ);
  setm(3, bb_w,      wbbT,  H,   H,   DEPTH);
  setm(4, img_w,     wimgT, H,   IMG, 1);
  setm(5, txt_w,     wtxtT, H,   TXT, 1);
  transpose_convert<<<cum, 256, 0, stream>>>(tp);

  gather_voxels<<<MP, 256, 0, stream>>>(vox, rowmap, Vs);
  hipMemsetAsync(T1acc, 0, (size_t)MP*BOT*4, stream);

  // K1: adapter down (split-K=8, atomic fp32 accum), then gelu+bias -> bf16
  gemm_bf16<EPI_ATOMIC><<<dim3(MT,1,8), 256, 0, stream>>>(
      Vs, IN, wadT, IN, (long long)IN*BOT, tileS, rowmap, IN/8,
      nullptr, 0, nullptr, 0, T1acc, nullptr, BOT);
  t1_epilogue<<<MP*BOT/256, 256, 0, stream>>>(T1acc, ad_down_b, rowmap, tileS, T1);

  // K2: adapter up + voxel residual + bias -> bf16 Hs
  gemm_bf16<EPI_RES_BF16><<<dim3(MT, IN/128, 1), 256, 0, stream>>>(
      T1, BOT, wupT, BOT, (long long)IN*BOT, tileS, rowmap, BOT,
      ad_up_b, IN, vox, IN, nullptr, Hs, IN);

  // K3: encoder linear -> fp32 Z, then LN+gelu -> Xf/Xb
  gemm_bf16<EPI_F32><<<dim3(MT, H/128, 1), 256, 0, stream>>>(
      Hs, IN, wencT, IN, (long long)IN*H, tileS, rowmap, IN,
      enc_b, H, nullptr, 0, Z, nullptr, H);
  ln_gelu_kernel<0><<<MP, 256, 0, stream>>>(Z, enc_ln_g, enc_ln_bb, H, tileS, rowmap, Xf, Xb);

  // backbone: 6 x (linear -> Z; X += gelu(ln(Z)))
  for (int d = 0; d < DEPTH; ++d){
    gemm_bf16<EPI_F32><<<dim3(MT, H/128, 1), 256, 0, stream>>>(
        Xb, H, wbbT + (size_t)d*H*H, H, 0, tileS, rowmap, H,
        bb_b + (size_t)d*H, 0, nullptr, 0, Z, nullptr, H);
    ln_gelu_kernel<1><<<MP, 256, 0, stream>>>(Z, bb_ln_g + (size_t)d*H, bb_ln_b + (size_t)d*H,
                                              0, tileS, rowmap, Xf, Xb);
  }

  // heads: scatter rows back to original order
  gemm_bf16<EPI_HEAD><<<dim3(MT, IMG/128, 1), 256, 0, stream>>>(
      Xb, H, wimgT, H, 0, tileS, rowmap, H,
      img_b, 0, nullptr, 0, out, nullptr, IMG);
  gemm_bf16<EPI_HEAD><<<dim3(MT, TXT/128, 1), 256, 0, stream>>>(
      Xb, H, wtxtT, H, 0, tileS, rowmap, H,
      txt_b, 0, nullptr, 0, out + (size_t)BATCH*IMG, nullptr, TXT);
}